// Round 3
// baseline (640.036 us; speedup 1.0000x reference)
//
#include <hip/hip_runtime.h>

// FSQ-style quantizer:
//   z:           [B, 6]  float32
//   percentiles: [8, 6]  float32 (sorted ascending per column)
//   codebook:    [262144, 64] float32
// Outputs (concatenated flat in d_out):
//   quantized: [B, 64] float32 = codebook[big_index]
//   big_index: [B]     written as float (exact: max 262143 < 2^24)
//
// index_d = clamp(count(z_d >= p[:,d]) - 1, 0, 7)
// big_index = sum_d index_d * 8^d  (== OR of idx << 3d)
//
// Round-2 fix: __builtin_nontemporal_* rejects HIP's float4 (a class); use a
// native ext_vector_type instead.
// Key idea (unchanged): output stores (520 MB/iter) are STREAMING — issue them
// nontemporal so they don't evict the 64 MB codebook from L2/L3. The random
// codebook gather then stays cache-resident. z is read exactly once ->
// nontemporal loads. One barrier per block; index computed redundantly by all
// 16 lanes of a gather group (48 compares is noise vs a barrier + LDS bounce).

#define NDIM 6
#define NLEV 8
#define CH 64
#define ROWS 256
#define THREADS 256

typedef float f32x4 __attribute__((ext_vector_type(4)));

__global__ __launch_bounds__(THREADS) void fsq_kernel(
    const float* __restrict__ z,
    const float* __restrict__ perc,
    const float* __restrict__ codebook,
    float* __restrict__ out_q,
    float* __restrict__ out_idx,
    int B)
{
    __shared__ float s_z[ROWS * NDIM];   // 6 KiB
    __shared__ float s_p[NLEV * NDIM];   // 192 B

    const int tid = threadIdx.x;
    const long long row0 = (long long)blockIdx.x * ROWS;

    if (tid < NLEV * NDIM) s_p[tid] = perc[tid];

    int nrows = ROWS;
    if (row0 + ROWS > (long long)B) nrows = (int)((long long)B - row0);

    if (nrows == ROWS) {
        // Full tile: vectorized 16B staging, nontemporal (z read exactly once).
        // ROWS*NDIM/4 = 384 vec4 loads across 256 threads (threads 0..127 do 2).
        const f32x4* __restrict__ zb = (const f32x4*)(z + row0 * NDIM);
        {
            f32x4 v = __builtin_nontemporal_load(&zb[tid]);
            ((f32x4*)s_z)[tid] = v;
        }
        if (tid < (ROWS * NDIM) / 4 - THREADS) {
            const int idx = tid + THREADS;
            f32x4 v = __builtin_nontemporal_load(&zb[idx]);
            ((f32x4*)s_z)[idx] = v;
        }
    } else {
        // Tail block: scalar staging.
        const float* __restrict__ zb = z + row0 * NDIM;
        for (int i = tid; i < nrows * NDIM; i += THREADS)
            s_z[i] = zb[i];
    }
    __syncthreads();

    const int lane = tid & 15;   // which 16B chunk of the 256B codebook row
    const int g    = tid >> 4;   // gather group = row within stripe of 16

    #pragma unroll 4
    for (int r = g; r < nrows; r += 16) {
        // All 16 lanes of the group compute the row index redundantly.
        // LDS reads are group-uniform -> broadcast, no bank conflicts.
        int big = 0;
        #pragma unroll
        for (int d = 0; d < NDIM; ++d) {
            const float zv = s_z[r * NDIM + d];
            int cnt = 0;
            #pragma unroll
            for (int j = 0; j < NLEV; ++j)
                cnt += (zv >= s_p[j * NDIM + d]) ? 1 : 0;
            int idx = cnt - 1;
            if (idx < 0) idx = 0;
            big |= idx << (3 * d);
        }

        // Gather 256 B codebook row (cache-resident once stores stop polluting),
        // stream the result out nontemporally (full 1 KB contiguous per wave).
        const f32x4* __restrict__ src = (const f32x4*)(codebook + (long long)big * CH);
        f32x4 v = src[lane];
        f32x4* __restrict__ dst = (f32x4*)(out_q + (row0 + r) * (long long)CH);
        __builtin_nontemporal_store(v, &dst[lane]);

        if (lane == 0) out_idx[row0 + r] = (float)big;  // 8 MB total, regular store
    }
}

extern "C" void kernel_launch(void* const* d_in, const int* in_sizes, int n_in,
                              void* d_out, int out_size, void* d_ws, size_t ws_size,
                              hipStream_t stream) {
    const float* z        = (const float*)d_in[0];
    const float* perc     = (const float*)d_in[1];
    const float* codebook = (const float*)d_in[2];

    const int B = in_sizes[0] / NDIM;   // 2,000,000

    float* out_q   = (float*)d_out;                       // [B, 64]
    float* out_idx = (float*)d_out + (long long)B * CH;   // [B]

    const int grid = (B + ROWS - 1) / ROWS;
    fsq_kernel<<<grid, THREADS, 0, stream>>>(z, perc, codebook, out_q, out_idx, B);
}